// Round 16
// baseline (1518.945 us; speedup 1.0000x reference)
//
#include <hip/hip_runtime.h>

constexpr int B_ = 8;
constexpr int N_ = 2048;
constexpr int K_ = 20;
constexpr float SLOPE_ = 0.2f;

typedef __attribute__((ext_vector_type(8))) short bf16x8;
typedef __attribute__((ext_vector_type(8))) _Float16 f16x8;
typedef __attribute__((ext_vector_type(4))) float f32x4;

__device__ __forceinline__ float lrelu(float v) { return v > 0.0f ? v : SLOPE_ * v; }

__device__ __forceinline__ void async16(const void* g, void* l) {
  __builtin_amdgcn_global_load_lds((const __attribute__((address_space(1))) unsigned int*)g,
                                   (__attribute__((address_space(3))) unsigned int*)l, 16, 0, 0);
}

__device__ __forceinline__ unsigned long long shflx64(unsigned long long v, int m) {
  return __shfl_xor(v, m, 64);
}

__device__ __forceinline__ unsigned short f2bf(float f) {
  unsigned u = __float_as_uint(f);
  u += 0x7fff + ((u >> 16) & 1);
  return (unsigned short)(u >> 16);
}

// fp32 -> fp16 (RNE) and back, via bit pattern.
__device__ __forceinline__ unsigned short f2h(float f) {
  _Float16 h = (_Float16)f;
  return __builtin_bit_cast(unsigned short, h);
}
__device__ __forceinline__ float h2f(unsigned short u) {
  return (float)__builtin_bit_cast(_Float16, u);
}

// Packed fragment-order layout (Pk), shared by producers and kNN:
//   chunk(b, tile=n/16, kk=c/32, split) at ((b*128+tile)*KK + kk)*2*512 u16
//   (+512 for split 1); within chunk: lane = (c%32/8)*16 + n%16, elem = c%8.
// kNN B-fragment lane l = cand row tile*16+(l&15), cols kk*32+(l>>4)*8 .. +8
// => B (and A!) read = chunk + l*8, a unit-stride 1KB wave load.

// Build Wp[2O x C]: rows [0,O) = Wd = W[:, :C]; rows [O,2O) = Wc - Wd.
// Optionally also emits bf16 Wp (layer-4 gemm_proj operand).
__global__ void prep_wp(const float* __restrict__ W, float* __restrict__ Wp,
                        unsigned short* __restrict__ Wp_bf, int O, int C) {
  int i = blockIdx.x * 256 + threadIdx.x;
  if (i >= 2 * O * C) return;
  int o = i / C, c = i - o * C;
  float v;
  if (o < O)
    v = W[o * 2 * C + c];
  else
    v = W[(o - O) * 2 * C + C + c] - W[(o - O) * 2 * C + c];
  Wp[i] = v;
  if (Wp_bf) Wp_bf[i] = f2bf(v);
}

// fp32 -> bf16 (RNE), vectorized x4, contiguous
__global__ void cvt_bf16(const float4* __restrict__ src, ushort4* __restrict__ dst, int n4) {
  int i = blockIdx.x * 256 + threadIdx.x;
  if (i >= n4) return;
  float4 v = src[i];
  ushort4 o = {f2bf(v.x), f2bf(v.y), f2bf(v.z), f2bf(v.w)};
  dst[i] = o;
}

// Layer-1 input: x (B*N*3 f32) -> C=32 zero-padded fp16 2-way Dekker splits,
// written DIRECTLY in packed fragment order (KK=1) + fused row norms.
__global__ void split32_x(const float* __restrict__ x, unsigned short* __restrict__ Pk1,
                          float* __restrict__ xx) {
  int id = blockIdx.x * 256 + threadIdx.x;
  if (id >= B_ * N_ * 32) return;
  int row = id >> 5, c = id & 31;
  float val = (c < 3) ? x[row * 3 + c] : 0.0f;
  unsigned short hb = f2h(val);
  float vh = h2f(hb);
  unsigned short mb = f2h(val - vh);  // Dekker residual, exact in fp32
  const int b = row >> 11, n = row & (N_ - 1);
  const int tile = n >> 4, rr = n & 15;
  const int lane = ((c >> 3) << 4) + rr, elem = c & 7;
  const size_t chunk = (size_t)(b * 128 + tile) * 2 * 512;  // KK=1
  Pk1[chunk + lane * 8 + elem] = hb;
  Pk1[chunk + 512 + lane * 8 + elem] = mb;
  float sq = val * val;
#pragma unroll
  for (int off = 16; off > 0; off >>= 1) sq += __shfl_xor(sq, off, 32);
  if (c == 0) xx[row] = sq;
}

// Selection for one query: r2[i] = d2 of cand i*64+lane, taken from an LDS row.
// Threshold (20th-smallest lane-min via bitonic) + ballot-compact + u64 bitonic
// sort; exact-pop fallback if cnt > 64. Verified machinery (R2-R15).
__device__ __forceinline__ void select_topk(const float* __restrict__ d2row, int lane,
                                            unsigned long long* __restrict__ cb,
                                            int* __restrict__ outp) {
  float r2[32];
#pragma unroll
  for (int i = 0; i < 32; i++) r2[i] = d2row[i * 64 + lane];

  const float INF = __int_as_float(0x7f800000);

  float lmin = r2[0];
#pragma unroll
  for (int i = 1; i < 32; i++) lmin = fminf(lmin, r2[i]);
  float sv = lmin;
#pragma unroll
  for (int k = 2; k <= 64; k <<= 1)
#pragma unroll
    for (int j = k >> 1; j > 0; j >>= 1) {
      float p = __shfl_xor(sv, j, 64);
      bool takeMax = ((lane & j) != 0) == ((lane & k) == 0);
      sv = takeMax ? fmaxf(sv, p) : fminf(sv, p);
    }
  float T = __shfl(sv, 19, 64);

  unsigned cnt = 0;
#pragma unroll
  for (int i = 0; i < 32; i++) {
    bool pred = r2[i] <= T;
    unsigned long long mk = __ballot(pred);
    if (mk) {
      int off = __popcll(mk & ((1ull << lane) - 1ull));
      unsigned pos = cnt + (unsigned)off;
      if (pred && pos < 64)
        cb[pos] = ((unsigned long long)__float_as_uint(r2[i]) << 32) | (unsigned)(i * 64 + lane);
      cnt += (unsigned)__popcll(mk);
    }
  }

  if (cnt <= 64) {
    unsigned long long v = (lane < (int)cnt) ? cb[lane] : ~0ull;
#pragma unroll
    for (int k = 2; k <= 64; k <<= 1)
#pragma unroll
      for (int j = k >> 1; j > 0; j >>= 1) {
        unsigned long long p = shflx64(v, j);
        bool takeMax = ((lane & j) != 0) == ((lane & k) == 0);
        bool lt = v < p;
        v = (takeMax == lt) ? p : v;
      }
    if (lane < K_) outp[lane] = (int)(unsigned)(v & 0xffffffffull);
  } else {
    for (int t2 = 0; t2 < K_; t2++) {
      unsigned long long loc = ~0ull;
#pragma unroll
      for (int i = 0; i < 32; i++) {
        unsigned long long u =
            ((unsigned long long)__float_as_uint(r2[i]) << 32) | (unsigned)(i * 64 + lane);
        loc = u < loc ? u : loc;
      }
#pragma unroll
      for (int off = 32; off > 0; off >>= 1) {
        unsigned long long vv = shflx64(loc, off);
        loc = vv < loc ? vv : loc;
      }
      const int mwin = (int)(unsigned)(loc & 0xffffffffull);
      if (lane == 0) outp[t2] = mwin;
#pragma unroll
      for (int i = 0; i < 32; i++)
        if (i * 64 + lane == mwin) r2[i] = INF;
    }
  }
}

// ---------------------------------------------------------------------------
// HYBRID kNN, all operands from the packed buffer. fp16 2-way Dekker split,
// 4 MFMA products (fp32-equivalent). Shapes:
//  - q16 (R8): 1024 thr / 16 waves / 4 w/SIMD; Q=16 (C=32 layer).
//  - q32 (R10/R16): 512 thr / 8 waves / 256-reg budget; Q=32 (C=64/128).
// R16: q32 ILP deepened — R15 counters showed ~50% L2-latency stall (MFMA 13us
// + VALU 16us of a 63.5us C=64 dispatch, loads unit-stride). B-ring DP 2->3
// (+8 VGPR, 6 loads in flight) and double-buffered A prefetch issued at t==8
// of the PRIOR kk (+16 VGPR, kills the synchronous reload bubble). Unified
// usage ~252 <= 256 (falsifier: WRITE_SIZE spill).
// ---------------------------------------------------------------------------
template <int C>
__global__ __launch_bounds__(1024, 4) void knn_mfma_q16(const unsigned short* __restrict__ Pk,
                                                        const float* __restrict__ xx,
                                                        int* __restrict__ idxo) {
  constexpr int KK = C / 32;
  constexpr int DP = 3;
  constexpr int NIT = KK * 8;
  const int b = blockIdx.x & 7;  // XCD-pinned batch
  const int q0 = (blockIdx.x >> 3) * 16;
  const int tid = threadIdx.x;
  const int w = tid >> 6, lane = tid & 63;
  const int bN = b * N_;
  const int lr = lane & 15;

  __shared__ float d2s[16][2052];
  __shared__ unsigned long long cbuf[16][64];

  const size_t qchunk = (size_t)(b * 128 + (q0 >> 4)) * KK * 2 * 512 + (size_t)lane * 8;
  f16x8 a2h[2], a2m[2];
  a2h[0] = *(const f16x8*)(Pk + qchunk);
  a2m[0] = *(const f16x8*)(Pk + qchunk + 512);

  f32x4 acc[8];
#pragma unroll
  for (int t = 0; t < 8; t++) acc[t] = (f32x4){0.0f, 0.0f, 0.0f, 0.0f};

  const size_t pbase = (size_t)b * (128 * KK * 2 * 512) + (size_t)lane * 8;
  f16x8 bh[DP], bm[DP];
#pragma unroll
  for (int i = 0; i < DP; i++) {
    const size_t a = pbase + (size_t)(((w * 8 + i) * KK + 0) * 2) * 512;
    bh[i] = *(const f16x8*)(Pk + a);
    bm[i] = *(const f16x8*)(Pk + a + 512);
  }
#pragma unroll
  for (int it = 0; it < NIT; it++) {
    const int kk = it >> 3, t = it & 7, s = it % DP;
    if (t == 0 && kk + 1 < KK) {
      const size_t qa = qchunk + (size_t)(kk + 1) * 2 * 512;
      a2h[(kk + 1) & 1] = *(const f16x8*)(Pk + qa);
      a2m[(kk + 1) & 1] = *(const f16x8*)(Pk + qa + 512);
    }
    f16x8 vh = bh[s], vm = bm[s];
    if (it + DP < NIT) {
      const int it2 = it + DP;
      const int kk2 = it2 >> 3, t2 = it2 & 7;
      const size_t a = pbase + (size_t)(((w * 8 + t2) * KK + kk2) * 2) * 512;
      bh[s] = *(const f16x8*)(Pk + a);
      bm[s] = *(const f16x8*)(Pk + a + 512);
    }
    const f16x8 ah = a2h[kk & 1], am = a2m[kk & 1];
    acc[t] = __builtin_amdgcn_mfma_f32_16x16x32_f16(ah, vh, acc[t], 0, 0, 0);  // hh
    acc[t] = __builtin_amdgcn_mfma_f32_16x16x32_f16(ah, vm, acc[t], 0, 0, 0);  // hm
    acc[t] = __builtin_amdgcn_mfma_f32_16x16x32_f16(am, vh, acc[t], 0, 0, 0);  // mh
    acc[t] = __builtin_amdgcn_mfma_f32_16x16x32_f16(am, vm, acc[t], 0, 0, 0);  // mm
  }

  float qn[4];
#pragma unroll
  for (int r = 0; r < 4; r++) qn[r] = xx[bN + q0 + (lane >> 4) * 4 + r];
#pragma unroll
  for (int t = 0; t < 8; t++) {
    float cn = xx[bN + (w * 8 + t) * 16 + lr];
#pragma unroll
    for (int r = 0; r < 4; r++) {
      float v = fmaxf(fmaf(-2.0f, acc[t][r], cn + qn[r]), 0.0f);
      d2s[(lane >> 4) * 4 + r][(w * 8 + t) * 16 + lr] = v;
    }
  }
  __syncthreads();
  select_topk(&d2s[w][0], lane, cbuf[w], idxo + (size_t)(bN + q0 + w) * K_);
}

template <int C>
__global__ __launch_bounds__(512, 2) void knn_mfma_q32(const unsigned short* __restrict__ Pk,
                                                       const float* __restrict__ xx,
                                                       int* __restrict__ idxo) {
  constexpr int KK = C / 32;
  constexpr int DP = 3;
  constexpr int NIT = KK * 16;
  const int b = blockIdx.x & 7;  // XCD-pinned batch
  const int q0 = (blockIdx.x >> 3) * 32;
  const int tid = threadIdx.x;
  const int w = tid >> 6, lane = tid & 63;
  const int bN = b * N_;
  const int lr = lane & 15;

  __shared__ float d2s[16][2052];
  __shared__ unsigned long long cbuf[8][64];

  const size_t qc0 = (size_t)(b * 128 + (q0 >> 4)) * KK * 2 * 512 + (size_t)lane * 8;
  const size_t qc1 = (size_t)(b * 128 + (q0 >> 4) + 1) * KK * 2 * 512 + (size_t)lane * 8;

  f32x4 acc0[16], acc1[16];
#pragma unroll
  for (int t = 0; t < 16; t++) {
    acc0[t] = (f32x4){0.0f, 0.0f, 0.0f, 0.0f};
    acc1[t] = (f32x4){0.0f, 0.0f, 0.0f, 0.0f};
  }

  // A fragments: double-buffered per kk (prefetch issued at t==8 of prior kk).
  f16x8 a2h0[2], a2m0[2], a2h1[2], a2m1[2];
  a2h0[0] = *(const f16x8*)(Pk + qc0);
  a2m0[0] = *(const f16x8*)(Pk + qc0 + 512);
  a2h1[0] = *(const f16x8*)(Pk + qc1);
  a2m1[0] = *(const f16x8*)(Pk + qc1 + 512);

  const size_t pbase = (size_t)b * (128 * KK * 2 * 512) + (size_t)lane * 8;
  f16x8 bh[DP], bm[DP];
#pragma unroll
  for (int i = 0; i < DP; i++) {
    const size_t a = pbase + (size_t)(((w * 16 + i) * KK + 0) * 2) * 512;
    bh[i] = *(const f16x8*)(Pk + a);
    bm[i] = *(const f16x8*)(Pk + a + 512);
  }
#pragma unroll
  for (int it = 0; it < NIT; it++) {
    const int kk = it >> 4, t = it & 15, s = it % DP;
    if (t == 8 && kk + 1 < KK) {  // prefetch NEXT kk's A (latency-covered)
      const int nb = (kk + 1) & 1;
      const size_t a0 = qc0 + (size_t)(kk + 1) * 2 * 512;
      const size_t a1 = qc1 + (size_t)(kk + 1) * 2 * 512;
      a2h0[nb] = *(const f16x8*)(Pk + a0);
      a2m0[nb] = *(const f16x8*)(Pk + a0 + 512);
      a2h1[nb] = *(const f16x8*)(Pk + a1);
      a2m1[nb] = *(const f16x8*)(Pk + a1 + 512);
    }
    f16x8 vh = bh[s], vm = bm[s];
    if (it + DP < NIT) {
      const int it2 = it + DP;
      const int kk2 = it2 >> 4, t2 = it2 & 15;
      const size_t a = pbase + (size_t)(((w * 16 + t2) * KK + kk2) * 2) * 512;
      bh[s] = *(const f16x8*)(Pk + a);
      bm[s] = *(const f16x8*)(Pk + a + 512);
    }
    const f16x8 ah0 = a2h0[kk & 1], am0 = a2m0[kk & 1];
    const f16x8 ah1 = a2h1[kk & 1], am1 = a2m1[kk & 1];
    acc0[t] = __builtin_amdgcn_mfma_f32_16x16x32_f16(ah0, vh, acc0[t], 0, 0, 0);  // hh
    acc0[t] = __builtin_amdgcn_mfma_f32_16x16x32_f16(ah0, vm, acc0[t], 0, 0, 0);  // hm
    acc0[t] = __builtin_amdgcn_mfma_f32_16x16x32_f16(am0, vh, acc0[t], 0, 0, 0);  // mh
    acc0[t] = __builtin_amdgcn_mfma_f32_16x16x32_f16(am0, vm, acc0[t], 0, 0, 0);  // mm
    acc1[t] = __builtin_amdgcn_mfma_f32_16x16x32_f16(ah1, vh, acc1[t], 0, 0, 0);
    acc1[t] = __builtin_amdgcn_mfma_f32_16x16x32_f16(ah1, vm, acc1[t], 0, 0, 0);
    acc1[t] = __builtin_amdgcn_mfma_f32_16x16x32_f16(am1, vh, acc1[t], 0, 0, 0);
    acc1[t] = __builtin_amdgcn_mfma_f32_16x16x32_f16(am1, vm, acc1[t], 0, 0, 0);
  }

  float qn0[4], qn1[4];
#pragma unroll
  for (int r = 0; r < 4; r++) {
    qn0[r] = xx[bN + q0 + (lane >> 4) * 4 + r];
    qn1[r] = xx[bN + q0 + 16 + (lane >> 4) * 4 + r];
  }

  // ---- phase 0: query group 0 ----
#pragma unroll
  for (int t = 0; t < 16; t++) {
    const int tt = w * 16 + t;
    float cn = xx[bN + tt * 16 + lr];
#pragma unroll
    for (int r = 0; r < 4; r++)
      d2s[(lane >> 4) * 4 + r][tt * 16 + lr] = fmaxf(fmaf(-2.0f, acc0[t][r], cn + qn0[r]), 0.0f);
  }
  __syncthreads();
  select_topk(&d2s[2 * w + 0][0], lane, cbuf[w], idxo + (size_t)(bN + q0 + 2 * w + 0) * K_);
  select_topk(&d2s[2 * w + 1][0], lane, cbuf[w], idxo + (size_t)(bN + q0 + 2 * w + 1) * K_);
  __syncthreads();

  // ---- phase 1: query group 1 ----
#pragma unroll
  for (int t = 0; t < 16; t++) {
    const int tt = w * 16 + t;
    float cn = xx[bN + tt * 16 + lr];
#pragma unroll
    for (int r = 0; r < 4; r++)
      d2s[(lane >> 4) * 4 + r][tt * 16 + lr] = fmaxf(fmaf(-2.0f, acc1[t][r], cn + qn1[r]), 0.0f);
  }
  __syncthreads();
  select_topk(&d2s[2 * w + 0][0], lane, cbuf[w], idxo + (size_t)(bN + q0 + 16 + 2 * w + 0) * K_);
  select_topk(&d2s[2 * w + 1][0], lane, cbuf[w], idxo + (size_t)(bN + q0 + 16 + 2 * w + 1) * K_);
}

// P[row, o'] = sum_c h[row, c] * Wp[o', c]; XCD-pinned row tiles.
template <int C, int O2>
__global__ void proj_kernel(const float* __restrict__ hin, int stride,
                            const float* __restrict__ Wp, float* __restrict__ P) {
  const int nt = (blockIdx.x & 7) * N_ + (blockIdx.x >> 3) * 16;  // XCD-pinned
  const int o = blockIdx.y * blockDim.x + threadIdx.x;
  __shared__ float hs[16][C];
  for (int i = threadIdx.x; i < 16 * C; i += blockDim.x) {
    int r = i / C, c = i - r * C;
    hs[r][c] = hin[(size_t)(nt + r) * stride + c];
  }
  __syncthreads();
  float acc[16];
#pragma unroll
  for (int t = 0; t < 16; t++) acc[t] = 0.0f;
  const float* wr = Wp + (size_t)o * C;
  if constexpr (C % 4 == 0) {
    for (int cg = 0; cg < C; cg += 4) {
      float4 w = *(const float4*)(wr + cg);
#pragma unroll
      for (int t = 0; t < 16; t++) {
        float4 h = *(const float4*)(&hs[t][cg]);
        acc[t] += w.x * h.x + w.y * h.y + w.z * h.z + w.w * h.w;
      }
    }
  } else {
    for (int c = 0; c < C; c++) {
      float w = wr[c];
#pragma unroll
      for (int t = 0; t < 16; t++) acc[t] += w * hs[t][c];
    }
  }
#pragma unroll
  for (int t = 0; t < 16; t++) P[(size_t)(nt + t) * O2 + o] = acc[t];
}

// Layer-4 proj via bf16 MFMA (K=128), XCD-pinned m-tiles.
__global__ __launch_bounds__(256) void gemm_proj(const unsigned short* __restrict__ A, int astride,
                                                 const unsigned short* __restrict__ Bw,
                                                 float* __restrict__ P) {
  const int m0 = ((blockIdx.x & 7) * 16 + (blockIdx.x >> 3)) * 128;  // XCD-pinned
  const int n0 = blockIdx.y * 128;
  const int tid = threadIdx.x;
  const int w = tid >> 6, lane = tid & 63;
  const int wm = w & 1, wn = w >> 1;

  __shared__ unsigned short lA[128 * 32];
  __shared__ unsigned short lB[128 * 32];

  const int r0 = (w * 2 + 0) * 16 + (lane >> 2);
  const int r1 = (w * 2 + 1) * 16 + (lane >> 2);
  const int ks = (lane & 3) * 8;
  const unsigned short* a0 = A + (size_t)(m0 + r0) * astride + ks;
  const unsigned short* a1 = A + (size_t)(m0 + r1) * astride + ks;
  const unsigned short* b0 = Bw + (size_t)(n0 + r0) * 128 + ks;
  const unsigned short* b1 = Bw + (size_t)(n0 + r1) * 128 + ks;
  unsigned short* lA0 = lA + (w * 2 + 0) * 512;
  unsigned short* lA1 = lA + (w * 2 + 1) * 512;
  unsigned short* lB0 = lB + (w * 2 + 0) * 512;
  unsigned short* lB1 = lB + (w * 2 + 1) * 512;

  f32x4 acc[4][4] = {};
  const int ka = (lane >> 4) * 8;

  for (int k0 = 0; k0 < 128; k0 += 32) {
    __syncthreads();
    async16(a0 + k0, lA0);
    async16(a1 + k0, lA1);
    async16(b0 + k0, lB0);
    async16(b1 + k0, lB1);
    __syncthreads();
    bf16x8 af[4], bfr[4];
#pragma unroll
    for (int mt = 0; mt < 4; mt++)
      af[mt] = *(const bf16x8*)&lA[(wm * 64 + mt * 16 + (lane & 15)) * 32 + ka];
#pragma unroll
    for (int nt = 0; nt < 4; nt++)
      bfr[nt] = *(const bf16x8*)&lB[(wn * 64 + nt * 16 + (lane & 15)) * 32 + ka];
#pragma unroll
    for (int mt = 0; mt < 4; mt++)
#pragma unroll
      for (int nt = 0; nt < 4; nt++)
        acc[mt][nt] = __builtin_amdgcn_mfma_f32_16x16x32_bf16(af[mt], bfr[nt], acc[mt][nt], 0, 0, 0);
  }

  const int col = n0 + wn * 64 + (lane & 15);
  const int rowb = m0 + wm * 64 + (lane >> 4) * 4;
#pragma unroll
  for (int mt = 0; mt < 4; mt++)
#pragma unroll
    for (int nt = 0; nt < 4; nt++)
#pragma unroll
      for (int r = 0; r < 4; r++)
        P[(size_t)(rowb + mt * 16 + r) * 512 + col + nt * 16] = acc[mt][nt][r];
}

// Combine: 256 threads handle ROWS=256/O rows; XCD-pinned.
// Emits: f32 hcat slice (hout), bf16 hcat slice (hbf), the next layer's kNN
// operands DIRECTLY in packed fragment order (pk; KK=O/32), and the bf16
// A-matrix for gemm_proj (a4).
template <int O>
__global__ __launch_bounds__(256) void combine_kernel(
    const float* __restrict__ P, const int* __restrict__ idxo, const float* __restrict__ bias,
    float* __restrict__ hout, unsigned short* __restrict__ hbf, float* __restrict__ xxo,
    unsigned short* __restrict__ pk, unsigned short* __restrict__ a4) {
  constexpr int ROWS = 256 / O;
  const int bb = blockIdx.x & 7;
  const int rt = blockIdx.x >> 3;
  const int r = threadIdx.x / O;
  const int o = threadIdx.x & (O - 1);
  const int row = bb * N_ + rt * ROWS + r;
  __shared__ int idxs[ROWS][K_];
  __shared__ float ps[ROWS][O / 64 > 0 ? O / 64 : 1];
  if (o < K_) idxs[r][o] = idxo[(size_t)row * K_ + o];
  __syncthreads();
  const int base_row = bb * N_;
  float g = -3.4e38f;
#pragma unroll
  for (int k = 0; k < K_; k++) {
    float v = P[(size_t)(base_row + idxs[r][k]) * (2 * O) + o];
    g = fmaxf(g, v);
  }
  float ba = P[(size_t)row * (2 * O) + O + o];
  float val = lrelu(g + ba + bias[o]);
  if (hout) hout[(size_t)row * 512 + o] = val;
  if (hbf) hbf[(size_t)row * 512 + o] = f2bf(val);
  if (pk) {
    unsigned short hb = f2h(val);
    float vh = h2f(hb);
    unsigned short mb = f2h(val - vh);  // Dekker residual, exact in fp32
    const int n = rt * ROWS + r;
    const int tile = n >> 4, rr = n & 15;
    const int kk = o >> 5, cc = o & 31;
    const int lane2 = ((cc >> 3) << 4) + rr, elem = cc & 7;
    const size_t chunk = ((size_t)(bb * 128 + tile) * (O / 32) + kk) * 2 * 512;
    pk[chunk + lane2 * 8 + elem] = hb;
    pk[chunk + 512 + lane2 * 8 + elem] = mb;
  }
  if (a4) a4[(size_t)row * 1024 + o] = f2bf(val);
  if (xxo) {
    float sq = val * val;
#pragma unroll
    for (int off = 32; off > 0; off >>= 1) sq += __shfl_xor(sq, off, 64);
    if constexpr (O == 64) {
      if (o == 0) xxo[row] = sq;
    } else {
      if ((threadIdx.x & 63) == 0) ps[r][o >> 6] = sq;
      __syncthreads();
      if (o == 0) {
        float t = ps[r][0];
#pragma unroll
        for (int u = 1; u < O / 64; u++) t += ps[r][u];
        xxo[row] = t;
      }
    }
  }
}

// Final GEMM: 128x128 tile, BK=32, bf16 MFMA, max-over-rows epilogue; XCD-pinned.
__global__ __launch_bounds__(256) void gemm_final(const unsigned short* __restrict__ A,
                                                  const unsigned short* __restrict__ Bw,
                                                  float* __restrict__ part) {
  const int mt5 = (blockIdx.x & 7) * 16 + (blockIdx.x >> 3);
  const int m0 = mt5 * 128;
  const int n0 = blockIdx.y * 128;
  const int tid = threadIdx.x;
  const int w = tid >> 6, lane = tid & 63;
  const int wm = w & 1, wn = w >> 1;

  __shared__ unsigned short lA[128 * 32];
  __shared__ unsigned short lB[128 * 32];
  __shared__ float ldsred[2][128];

  const int r0 = (w * 2 + 0) * 16 + (lane >> 2);
  const int r1 = (w * 2 + 1) * 16 + (lane >> 2);
  const int ks = (lane & 3) * 8;
  const unsigned short* a0 = A + (size_t)(m0 + r0) * 512 + ks;
  const unsigned short* a1 = A + (size_t)(m0 + r1) * 512 + ks;
  const unsigned short* b0 = Bw + (size_t)(n0 + r0) * 512 + ks;
  const unsigned short* b1 = Bw + (size_t)(n0 + r1) * 512 + ks;
  unsigned short* lA0 = lA + (w * 2 + 0) * 512;
  unsigned short* lA1 = lA + (w * 2 + 1) * 512;
  unsigned short* lB0 = lB + (w * 2 + 0) * 512;
  unsigned short* lB1 = lB + (w * 2 + 1) * 512;

  f32x4 acc[4][4] = {};
  const int ka = (lane >> 4) * 8;

  for (int k0 = 0; k0 < 512; k0 += 32) {
    __syncthreads();
    async16(a0 + k0, lA0);
    async16(a1 + k0, lA1);
    async16(b0 + k0, lB0);
    async16(b1 + k0, lB1);
    __syncthreads();
    bf16x8 af[4], bfr[4];
#pragma unroll
    for (int mt = 0; mt < 4; mt++)
      af[mt] = *(const bf16x8*)&lA[(wm * 64 + mt * 16 + (lane & 15)) * 32 + ka];
#pragma unroll
    for (int nt = 0; nt < 4; nt++)
      bfr[nt] = *(const bf16x8*)&lB[(wn * 64 + nt * 16 + (lane & 15)) * 32 + ka];
#pragma unroll
    for (int mt = 0; mt < 4; mt++)
#pragma unroll
      for (int nt = 0; nt < 4; nt++)
        acc[mt][nt] = __builtin_amdgcn_mfma_f32_16x16x32_bf16(af[mt], bfr[nt], acc[mt][nt], 0, 0, 0);
  }

#pragma unroll
  for (int nt = 0; nt < 4; nt++) {
    float v = -3.4e38f;
#pragma unroll
    for (int mt = 0; mt < 4; mt++)
#pragma unroll
      for (int r = 0; r < 4; r++) v = fmaxf(v, acc[mt][nt][r]);
    v = fmaxf(v, __shfl_xor(v, 16, 64));
    v = fmaxf(v, __shfl_xor(v, 32, 64));
    if (lane < 16) ldsred[wm][wn * 64 + nt * 16 + lane] = v;
  }
  __syncthreads();
  if (tid < 128) {
    float v = fmaxf(ldsred[0][tid], ldsred[1][tid]);
    const int b = blockIdx.x & 7, s5 = blockIdx.x >> 3;
    part[(size_t)(b * 16 + s5) * 1024 + n0 + tid] = v;
  }
}

__global__ void final_reduce(const float* __restrict__ part, const float* __restrict__ bf,
                             float* __restrict__ out) {
  int i = blockIdx.x * 256 + threadIdx.x;
  if (i >= B_ * 1024) return;
  int b = i >> 10, o = i & 1023;
  float m = -3.4e38f;
  for (int s = 0; s < 16; s++) m = fmaxf(m, part[(size_t)(b * 16 + s) * 1024 + o]);
  out[i] = lrelu(m + bf[o]);
}

extern "C" void kernel_launch(void* const* d_in, const int* in_sizes, int n_in, void* d_out,
                              int out_size, void* d_ws, size_t ws_size, hipStream_t stream) {
  (void)in_sizes; (void)n_in; (void)out_size;
  const float* x = (const float*)d_in[0];
  const float* W1 = (const float*)d_in[1];
  const float* b1 = (const float*)d_in[2];
  const float* W2 = (const float*)d_in[3];
  const float* b2 = (const float*)d_in[4];
  const float* W3 = (const float*)d_in[5];
  const float* b3 = (const float*)d_in[6];
  const float* W4 = (const float*)d_in[7];
  const float* b4 = (const float*)d_in[8];
  const float* Wf = (const float*)d_in[9];
  const float* bf = (const float*)d_in[10];

  float* ws = (float*)d_ws;
  float* hcat = ws;                               // B*N*512 floats (32 MB)
  float* P = hcat + (size_t)B_ * N_ * 512;        // B*N*512 floats (32 MB)
  int* idx = (int*)(P + (size_t)B_ * N_ * 512);   // B*N*20 ints
  float* Wp = (float*)(idx + (size_t)B_ * N_ * K_);
  float* part = Wp + 512 * 128;                   // 8*16*1024 floats
  float* xxb = part + 8 * 16 * 1024;              // B*N floats (row norms)
  float* out = (float*)d_out;
  unsigned short* hcat_bf = (unsigned short*)P;   // alias P (dead after layer-4)
  unsigned short* Wf_bf = hcat_bf + (size_t)B_ * N_ * 512;
  unsigned short* A4_bf = (unsigned short*)hcat + 512;  // interleaved, stride 1024 ushorts
  unsigned short* Wp_bf = (unsigned short*)part;        // part dead until gemm_final

  // Optional fused-bf16 hcat buffer (16 MB) past xxb; used only if ws fits.
  float* ws_end = xxb + (size_t)B_ * N_;
  unsigned short* hcatbf2 = (unsigned short*)ws_end;
  const size_t need = ((char*)(hcatbf2 + (size_t)B_ * N_ * 512)) - (char*)d_ws;
  const bool fused = ws_size >= need;

  // Packed kNN operand buffers (producers write fragment order directly):
  //   Pk23 at P+8MB (C=32 layer-1: 2MB; C=64 layers 2-3: 4MB);
  //   Pk4  at P+16MB (C=128: 8MB).
  unsigned short* Pk23 = (unsigned short*)(P + (size_t)2097152);  // +8 MB
  unsigned short* Pk4 = (unsigned short*)(P + (size_t)4194304);   // +16 MB

  dim3 knng16(N_ / 16 * B_);   // Q=16: 1024 blocks x 1024 thr
  dim3 knng32q(N_ / 32 * B_);  // Q=32: 512 blocks x 512 thr

  // Layer 1: C=3 (padded to 32) -> O=64; q16 kNN (selection-bound layer).
  prep_wp<<<(2 * 64 * 3 + 255) / 256, 256, 0, stream>>>(W1, Wp, nullptr, 64, 3);
  split32_x<<<(B_ * N_ * 32 + 255) / 256, 256, 0, stream>>>(x, Pk23, xxb);
  knn_mfma_q16<32><<<knng16, 1024, 0, stream>>>(Pk23, xxb, idx);
  proj_kernel<3, 128><<<dim3(B_ * N_ / 16, 1), 128, 0, stream>>>(x, 3, Wp, P);
  combine_kernel<64><<<B_ * N_ / 4, 256, 0, stream>>>(
      P, idx, b1, hcat + 0, fused ? hcatbf2 + 0 : nullptr, xxb, Pk23, nullptr);

  // Layer 2: C=64 -> O=64; q32 kNN.
  prep_wp<<<(2 * 64 * 64 + 255) / 256, 256, 0, stream>>>(W2, Wp, nullptr, 64, 64);
  knn_mfma_q32<64><<<knng32q, 512, 0, stream>>>(Pk23, xxb, idx);
  proj_kernel<64, 128><<<dim3(B_ * N_ / 16, 1), 128, 0, stream>>>(hcat + 0, 512, Wp, P);
  combine_kernel<64><<<B_ * N_ / 4, 256, 0, stream>>>(
      P, idx, b2, hcat + 64, fused ? hcatbf2 + 64 : nullptr, xxb, Pk23, nullptr);

  // Layer 3: C=64 -> O=128; q32 kNN.
  prep_wp<<<(2 * 128 * 64 + 255) / 256, 256, 0, stream>>>(W3, Wp, nullptr, 128, 64);
  knn_mfma_q32<64><<<knng32q, 512, 0, stream>>>(Pk23, xxb, idx);
  proj_kernel<64, 256><<<dim3(B_ * N_ / 16, 1), 256, 0, stream>>>(hcat + 64, 512, Wp, P);
  combine_kernel<128><<<B_ * N_ / 2, 256, 0, stream>>>(
      P, idx, b3, fused ? nullptr : hcat + 128, fused ? hcatbf2 + 128 : nullptr, xxb, Pk4,
      A4_bf);

  // Layer 4: C=128 -> O=256; q32 kNN; proj via bf16 MFMA (prep_wp emits bf16).
  prep_wp<<<(2 * 256 * 128 + 255) / 256, 256, 0, stream>>>(W4, Wp, Wp_bf, 256, 128);
  knn_mfma_q32<128><<<knng32q, 512, 0, stream>>>(Pk4, xxb, idx);
  gemm_proj<<<dim3(B_ * N_ / 128, 4), 256, 0, stream>>>(A4_bf, 1024, Wp_bf, P);
  combine_kernel<256><<<B_ * N_, 256, 0, stream>>>(
      P, idx, b4, fused ? nullptr : hcat + 256, fused ? hcatbf2 + 256 : nullptr, nullptr,
      nullptr, nullptr);

  // Final 1x1 conv via bf16 MFMA + fused max-over-rows.
  if (!fused)
    cvt_bf16<<<(B_ * N_ * 512 / 4 + 255) / 256, 256, 0, stream>>>(
        (const float4*)hcat, (ushort4*)hcat_bf, B_ * N_ * 512 / 4);
  cvt_bf16<<<(1024 * 512 / 4 + 255) / 256, 256, 0, stream>>>(
      (const float4*)Wf, (ushort4*)Wf_bf, 1024 * 512 / 4);
  gemm_final<<<dim3(128, 8), 256, 0, stream>>>(fused ? hcatbf2 : hcat_bf, Wf_bf, part);
  final_reduce<<<(B_ * 1024 + 255) / 256, 256, 0, stream>>>(part, bf, out);
}

// Round 17
// 406.846 us; speedup vs baseline: 3.7335x; 3.7335x over previous
//
#include <hip/hip_runtime.h>

constexpr int B_ = 8;
constexpr int N_ = 2048;
constexpr int K_ = 20;
constexpr float SLOPE_ = 0.2f;

typedef __attribute__((ext_vector_type(8))) short bf16x8;
typedef __attribute__((ext_vector_type(8))) _Float16 f16x8;
typedef __attribute__((ext_vector_type(4))) float f32x4;

__device__ __forceinline__ float lrelu(float v) { return v > 0.0f ? v : SLOPE_ * v; }

__device__ __forceinline__ void async16(const void* g, void* l) {
  __builtin_amdgcn_global_load_lds((const __attribute__((address_space(1))) unsigned int*)g,
                                   (__attribute__((address_space(3))) unsigned int*)l, 16, 0, 0);
}

__device__ __forceinline__ unsigned long long shflx64(unsigned long long v, int m) {
  return __shfl_xor(v, m, 64);
}

__device__ __forceinline__ unsigned short f2bf(float f) {
  unsigned u = __float_as_uint(f);
  u += 0x7fff + ((u >> 16) & 1);
  return (unsigned short)(u >> 16);
}

// fp32 -> fp16 (RNE) and back, via bit pattern.
__device__ __forceinline__ unsigned short f2h(float f) {
  _Float16 h = (_Float16)f;
  return __builtin_bit_cast(unsigned short, h);
}
__device__ __forceinline__ float h2f(unsigned short u) {
  return (float)__builtin_bit_cast(_Float16, u);
}

// Packed fragment-order layout (Pk), shared by producers and kNN:
//   chunk(b, tile=n/16, kk=c/32, split) at ((b*128+tile)*KK + kk)*2*512 u16
//   (+512 for split 1); within chunk: lane = (c%32/8)*16 + n%16, elem = c%8.
// kNN B-fragment lane l = cand row tile*16+(l&15), cols kk*32+(l>>4)*8 .. +8
// => B (and A!) read = chunk + l*8, a unit-stride 1KB wave load.

// Build Wp[2O x C]: rows [0,O) = Wd = W[:, :C]; rows [O,2O) = Wc - Wd.
// Optionally also emits bf16 Wp (layer-4 gemm_proj operand).
__global__ void prep_wp(const float* __restrict__ W, float* __restrict__ Wp,
                        unsigned short* __restrict__ Wp_bf, int O, int C) {
  int i = blockIdx.x * 256 + threadIdx.x;
  if (i >= 2 * O * C) return;
  int o = i / C, c = i - o * C;
  float v;
  if (o < O)
    v = W[o * 2 * C + c];
  else
    v = W[(o - O) * 2 * C + C + c] - W[(o - O) * 2 * C + c];
  Wp[i] = v;
  if (Wp_bf) Wp_bf[i] = f2bf(v);
}

// fp32 -> bf16 (RNE), vectorized x4, contiguous
__global__ void cvt_bf16(const float4* __restrict__ src, ushort4* __restrict__ dst, int n4) {
  int i = blockIdx.x * 256 + threadIdx.x;
  if (i >= n4) return;
  float4 v = src[i];
  ushort4 o = {f2bf(v.x), f2bf(v.y), f2bf(v.z), f2bf(v.w)};
  dst[i] = o;
}

// Layer-1 input: x (B*N*3 f32) -> C=32 zero-padded fp16 2-way Dekker splits,
// written DIRECTLY in packed fragment order (KK=1) + fused row norms.
__global__ void split32_x(const float* __restrict__ x, unsigned short* __restrict__ Pk1,
                          float* __restrict__ xx) {
  int id = blockIdx.x * 256 + threadIdx.x;
  if (id >= B_ * N_ * 32) return;
  int row = id >> 5, c = id & 31;
  float val = (c < 3) ? x[row * 3 + c] : 0.0f;
  unsigned short hb = f2h(val);
  float vh = h2f(hb);
  unsigned short mb = f2h(val - vh);  // Dekker residual, exact in fp32
  const int b = row >> 11, n = row & (N_ - 1);
  const int tile = n >> 4, rr = n & 15;
  const int lane = ((c >> 3) << 4) + rr, elem = c & 7;
  const size_t chunk = (size_t)(b * 128 + tile) * 2 * 512;  // KK=1
  Pk1[chunk + lane * 8 + elem] = hb;
  Pk1[chunk + 512 + lane * 8 + elem] = mb;
  float sq = val * val;
#pragma unroll
  for (int off = 16; off > 0; off >>= 1) sq += __shfl_xor(sq, off, 32);
  if (c == 0) xx[row] = sq;
}

// Selection for one query: r2[i] = d2 of cand i*64+lane, taken from an LDS row.
// Threshold (20th-smallest lane-min via bitonic) + ballot-compact + u64 bitonic
// sort; exact-pop fallback if cnt > 64. Verified machinery (R2-R15).
__device__ __forceinline__ void select_topk(const float* __restrict__ d2row, int lane,
                                            unsigned long long* __restrict__ cb,
                                            int* __restrict__ outp) {
  float r2[32];
#pragma unroll
  for (int i = 0; i < 32; i++) r2[i] = d2row[i * 64 + lane];

  const float INF = __int_as_float(0x7f800000);

  float lmin = r2[0];
#pragma unroll
  for (int i = 1; i < 32; i++) lmin = fminf(lmin, r2[i]);
  float sv = lmin;
#pragma unroll
  for (int k = 2; k <= 64; k <<= 1)
#pragma unroll
    for (int j = k >> 1; j > 0; j >>= 1) {
      float p = __shfl_xor(sv, j, 64);
      bool takeMax = ((lane & j) != 0) == ((lane & k) == 0);
      sv = takeMax ? fmaxf(sv, p) : fminf(sv, p);
    }
  float T = __shfl(sv, 19, 64);

  unsigned cnt = 0;
#pragma unroll
  for (int i = 0; i < 32; i++) {
    bool pred = r2[i] <= T;
    unsigned long long mk = __ballot(pred);
    if (mk) {
      int off = __popcll(mk & ((1ull << lane) - 1ull));
      unsigned pos = cnt + (unsigned)off;
      if (pred && pos < 64)
        cb[pos] = ((unsigned long long)__float_as_uint(r2[i]) << 32) | (unsigned)(i * 64 + lane);
      cnt += (unsigned)__popcll(mk);
    }
  }

  if (cnt <= 64) {
    unsigned long long v = (lane < (int)cnt) ? cb[lane] : ~0ull;
#pragma unroll
    for (int k = 2; k <= 64; k <<= 1)
#pragma unroll
      for (int j = k >> 1; j > 0; j >>= 1) {
        unsigned long long p = shflx64(v, j);
        bool takeMax = ((lane & j) != 0) == ((lane & k) == 0);
        bool lt = v < p;
        v = (takeMax == lt) ? p : v;
      }
    if (lane < K_) outp[lane] = (int)(unsigned)(v & 0xffffffffull);
  } else {
    for (int t2 = 0; t2 < K_; t2++) {
      unsigned long long loc = ~0ull;
#pragma unroll
      for (int i = 0; i < 32; i++) {
        unsigned long long u =
            ((unsigned long long)__float_as_uint(r2[i]) << 32) | (unsigned)(i * 64 + lane);
        loc = u < loc ? u : loc;
      }
#pragma unroll
      for (int off = 32; off > 0; off >>= 1) {
        unsigned long long vv = shflx64(loc, off);
        loc = vv < loc ? vv : loc;
      }
      const int mwin = (int)(unsigned)(loc & 0xffffffffull);
      if (lane == 0) outp[t2] = mwin;
#pragma unroll
      for (int i = 0; i < 32; i++)
        if (i * 64 + lane == mwin) r2[i] = INF;
    }
  }
}

// ---------------------------------------------------------------------------
// HYBRID kNN, all operands from the packed buffer (A-fragment = chunk+lane*8,
// same permutation as B — see layout comment above). fp16 2-way Dekker split,
// 4 MFMA products (fp32-equivalent). Shapes:
//  - q16 (R8): 1024 thr / 16 waves / 4 w/SIMD; Q=16 (C=32 layer).
//  - q32 (R10): 512 thr / 8 waves / 256-reg budget; Q=32 (C=64/128 layers).
// R16 lesson: q32 is AT the 256-reg ceiling (DP=2, sync A reload); any added
// per-wave state (DP=3, A dbuf) spills (WRITE_SIZE 59MB, 3x regression).
// This is R15's verified configuration.
// ---------------------------------------------------------------------------
template <int C>
__global__ __launch_bounds__(1024, 4) void knn_mfma_q16(const unsigned short* __restrict__ Pk,
                                                        const float* __restrict__ xx,
                                                        int* __restrict__ idxo) {
  constexpr int KK = C / 32;
  constexpr int DP = 3;
  constexpr int NIT = KK * 8;
  const int b = blockIdx.x & 7;  // XCD-pinned batch
  const int q0 = (blockIdx.x >> 3) * 16;
  const int tid = threadIdx.x;
  const int w = tid >> 6, lane = tid & 63;
  const int bN = b * N_;
  const int lr = lane & 15;

  __shared__ float d2s[16][2052];
  __shared__ unsigned long long cbuf[16][64];

  const size_t qchunk = (size_t)(b * 128 + (q0 >> 4)) * KK * 2 * 512 + (size_t)lane * 8;
  f16x8 a2h[2], a2m[2];
  a2h[0] = *(const f16x8*)(Pk + qchunk);
  a2m[0] = *(const f16x8*)(Pk + qchunk + 512);

  f32x4 acc[8];
#pragma unroll
  for (int t = 0; t < 8; t++) acc[t] = (f32x4){0.0f, 0.0f, 0.0f, 0.0f};

  const size_t pbase = (size_t)b * (128 * KK * 2 * 512) + (size_t)lane * 8;
  f16x8 bh[DP], bm[DP];
#pragma unroll
  for (int i = 0; i < DP; i++) {
    const size_t a = pbase + (size_t)(((w * 8 + i) * KK + 0) * 2) * 512;
    bh[i] = *(const f16x8*)(Pk + a);
    bm[i] = *(const f16x8*)(Pk + a + 512);
  }
#pragma unroll
  for (int it = 0; it < NIT; it++) {
    const int kk = it >> 3, t = it & 7, s = it % DP;
    if (t == 0 && kk + 1 < KK) {
      const size_t qa = qchunk + (size_t)(kk + 1) * 2 * 512;
      a2h[(kk + 1) & 1] = *(const f16x8*)(Pk + qa);
      a2m[(kk + 1) & 1] = *(const f16x8*)(Pk + qa + 512);
    }
    f16x8 vh = bh[s], vm = bm[s];
    if (it + DP < NIT) {
      const int it2 = it + DP;
      const int kk2 = it2 >> 3, t2 = it2 & 7;
      const size_t a = pbase + (size_t)(((w * 8 + t2) * KK + kk2) * 2) * 512;
      bh[s] = *(const f16x8*)(Pk + a);
      bm[s] = *(const f16x8*)(Pk + a + 512);
    }
    const f16x8 ah = a2h[kk & 1], am = a2m[kk & 1];
    acc[t] = __builtin_amdgcn_mfma_f32_16x16x32_f16(ah, vh, acc[t], 0, 0, 0);  // hh
    acc[t] = __builtin_amdgcn_mfma_f32_16x16x32_f16(ah, vm, acc[t], 0, 0, 0);  // hm
    acc[t] = __builtin_amdgcn_mfma_f32_16x16x32_f16(am, vh, acc[t], 0, 0, 0);  // mh
    acc[t] = __builtin_amdgcn_mfma_f32_16x16x32_f16(am, vm, acc[t], 0, 0, 0);  // mm
  }

  float qn[4];
#pragma unroll
  for (int r = 0; r < 4; r++) qn[r] = xx[bN + q0 + (lane >> 4) * 4 + r];
#pragma unroll
  for (int t = 0; t < 8; t++) {
    float cn = xx[bN + (w * 8 + t) * 16 + lr];
#pragma unroll
    for (int r = 0; r < 4; r++) {
      float v = fmaxf(fmaf(-2.0f, acc[t][r], cn + qn[r]), 0.0f);
      d2s[(lane >> 4) * 4 + r][(w * 8 + t) * 16 + lr] = v;
    }
  }
  __syncthreads();
  select_topk(&d2s[w][0], lane, cbuf[w], idxo + (size_t)(bN + q0 + w) * K_);
}

template <int C>
__global__ __launch_bounds__(512, 2) void knn_mfma_q32(const unsigned short* __restrict__ Pk,
                                                       const float* __restrict__ xx,
                                                       int* __restrict__ idxo) {
  constexpr int KK = C / 32;
  constexpr int NIT = KK * 16;
  const int b = blockIdx.x & 7;  // XCD-pinned batch
  const int q0 = (blockIdx.x >> 3) * 32;
  const int tid = threadIdx.x;
  const int w = tid >> 6, lane = tid & 63;
  const int bN = b * N_;
  const int lr = lane & 15;

  __shared__ float d2s[16][2052];
  __shared__ unsigned long long cbuf[8][64];

  const size_t qc0 = (size_t)(b * 128 + (q0 >> 4)) * KK * 2 * 512 + (size_t)lane * 8;
  const size_t qc1 = (size_t)(b * 128 + (q0 >> 4) + 1) * KK * 2 * 512 + (size_t)lane * 8;

  f32x4 acc0[16], acc1[16];
#pragma unroll
  for (int t = 0; t < 16; t++) {
    acc0[t] = (f32x4){0.0f, 0.0f, 0.0f, 0.0f};
    acc1[t] = (f32x4){0.0f, 0.0f, 0.0f, 0.0f};
  }

  const size_t pbase = (size_t)b * (128 * KK * 2 * 512) + (size_t)lane * 8;
  f16x8 bh[2], bm[2];
#pragma unroll
  for (int i = 0; i < 2; i++) {
    const size_t a = pbase + (size_t)(((w * 16 + i) * KK + 0) * 2) * 512;
    bh[i] = *(const f16x8*)(Pk + a);
    bm[i] = *(const f16x8*)(Pk + a + 512);
  }
  f16x8 ah0, am0, ah1, am1;
#pragma unroll
  for (int it = 0; it < NIT; it++) {
    const int kk = it >> 4, t = it & 15, s = it & 1;
    if (t == 0) {  // reload A fragments for this kk (both query groups)
      const size_t a0 = qc0 + (size_t)kk * 2 * 512;
      const size_t a1 = qc1 + (size_t)kk * 2 * 512;
      ah0 = *(const f16x8*)(Pk + a0);
      am0 = *(const f16x8*)(Pk + a0 + 512);
      ah1 = *(const f16x8*)(Pk + a1);
      am1 = *(const f16x8*)(Pk + a1 + 512);
    }
    f16x8 vh = bh[s], vm = bm[s];
    if (it + 2 < NIT) {
      const int it2 = it + 2;
      const int kk2 = it2 >> 4, t2 = it2 & 15;
      const size_t a = pbase + (size_t)(((w * 16 + t2) * KK + kk2) * 2) * 512;
      bh[s] = *(const f16x8*)(Pk + a);
      bm[s] = *(const f16x8*)(Pk + a + 512);
    }
    acc0[t] = __builtin_amdgcn_mfma_f32_16x16x32_f16(ah0, vh, acc0[t], 0, 0, 0);  // hh
    acc0[t] = __builtin_amdgcn_mfma_f32_16x16x32_f16(ah0, vm, acc0[t], 0, 0, 0);  // hm
    acc0[t] = __builtin_amdgcn_mfma_f32_16x16x32_f16(am0, vh, acc0[t], 0, 0, 0);  // mh
    acc0[t] = __builtin_amdgcn_mfma_f32_16x16x32_f16(am0, vm, acc0[t], 0, 0, 0);  // mm
    acc1[t] = __builtin_amdgcn_mfma_f32_16x16x32_f16(ah1, vh, acc1[t], 0, 0, 0);
    acc1[t] = __builtin_amdgcn_mfma_f32_16x16x32_f16(ah1, vm, acc1[t], 0, 0, 0);
    acc1[t] = __builtin_amdgcn_mfma_f32_16x16x32_f16(am1, vh, acc1[t], 0, 0, 0);
    acc1[t] = __builtin_amdgcn_mfma_f32_16x16x32_f16(am1, vm, acc1[t], 0, 0, 0);
  }

  float qn0[4], qn1[4];
#pragma unroll
  for (int r = 0; r < 4; r++) {
    qn0[r] = xx[bN + q0 + (lane >> 4) * 4 + r];
    qn1[r] = xx[bN + q0 + 16 + (lane >> 4) * 4 + r];
  }

  // ---- phase 0: query group 0 ----
#pragma unroll
  for (int t = 0; t < 16; t++) {
    const int tt = w * 16 + t;
    float cn = xx[bN + tt * 16 + lr];
#pragma unroll
    for (int r = 0; r < 4; r++)
      d2s[(lane >> 4) * 4 + r][tt * 16 + lr] = fmaxf(fmaf(-2.0f, acc0[t][r], cn + qn0[r]), 0.0f);
  }
  __syncthreads();
  select_topk(&d2s[2 * w + 0][0], lane, cbuf[w], idxo + (size_t)(bN + q0 + 2 * w + 0) * K_);
  select_topk(&d2s[2 * w + 1][0], lane, cbuf[w], idxo + (size_t)(bN + q0 + 2 * w + 1) * K_);
  __syncthreads();

  // ---- phase 1: query group 1 ----
#pragma unroll
  for (int t = 0; t < 16; t++) {
    const int tt = w * 16 + t;
    float cn = xx[bN + tt * 16 + lr];
#pragma unroll
    for (int r = 0; r < 4; r++)
      d2s[(lane >> 4) * 4 + r][tt * 16 + lr] = fmaxf(fmaf(-2.0f, acc1[t][r], cn + qn1[r]), 0.0f);
  }
  __syncthreads();
  select_topk(&d2s[2 * w + 0][0], lane, cbuf[w], idxo + (size_t)(bN + q0 + 16 + 2 * w + 0) * K_);
  select_topk(&d2s[2 * w + 1][0], lane, cbuf[w], idxo + (size_t)(bN + q0 + 16 + 2 * w + 1) * K_);
}

// P[row, o'] = sum_c h[row, c] * Wp[o', c]; XCD-pinned row tiles.
template <int C, int O2>
__global__ void proj_kernel(const float* __restrict__ hin, int stride,
                            const float* __restrict__ Wp, float* __restrict__ P) {
  const int nt = (blockIdx.x & 7) * N_ + (blockIdx.x >> 3) * 16;  // XCD-pinned
  const int o = blockIdx.y * blockDim.x + threadIdx.x;
  __shared__ float hs[16][C];
  for (int i = threadIdx.x; i < 16 * C; i += blockDim.x) {
    int r = i / C, c = i - r * C;
    hs[r][c] = hin[(size_t)(nt + r) * stride + c];
  }
  __syncthreads();
  float acc[16];
#pragma unroll
  for (int t = 0; t < 16; t++) acc[t] = 0.0f;
  const float* wr = Wp + (size_t)o * C;
  if constexpr (C % 4 == 0) {
    for (int cg = 0; cg < C; cg += 4) {
      float4 w = *(const float4*)(wr + cg);
#pragma unroll
      for (int t = 0; t < 16; t++) {
        float4 h = *(const float4*)(&hs[t][cg]);
        acc[t] += w.x * h.x + w.y * h.y + w.z * h.z + w.w * h.w;
      }
    }
  } else {
    for (int c = 0; c < C; c++) {
      float w = wr[c];
#pragma unroll
      for (int t = 0; t < 16; t++) acc[t] += w * hs[t][c];
    }
  }
#pragma unroll
  for (int t = 0; t < 16; t++) P[(size_t)(nt + t) * O2 + o] = acc[t];
}

// Layer-4 proj via bf16 MFMA (K=128), XCD-pinned m-tiles.
__global__ __launch_bounds__(256) void gemm_proj(const unsigned short* __restrict__ A, int astride,
                                                 const unsigned short* __restrict__ Bw,
                                                 float* __restrict__ P) {
  const int m0 = ((blockIdx.x & 7) * 16 + (blockIdx.x >> 3)) * 128;  // XCD-pinned
  const int n0 = blockIdx.y * 128;
  const int tid = threadIdx.x;
  const int w = tid >> 6, lane = tid & 63;
  const int wm = w & 1, wn = w >> 1;

  __shared__ unsigned short lA[128 * 32];
  __shared__ unsigned short lB[128 * 32];

  const int r0 = (w * 2 + 0) * 16 + (lane >> 2);
  const int r1 = (w * 2 + 1) * 16 + (lane >> 2);
  const int ks = (lane & 3) * 8;
  const unsigned short* a0 = A + (size_t)(m0 + r0) * astride + ks;
  const unsigned short* a1 = A + (size_t)(m0 + r1) * astride + ks;
  const unsigned short* b0 = Bw + (size_t)(n0 + r0) * 128 + ks;
  const unsigned short* b1 = Bw + (size_t)(n0 + r1) * 128 + ks;
  unsigned short* lA0 = lA + (w * 2 + 0) * 512;
  unsigned short* lA1 = lA + (w * 2 + 1) * 512;
  unsigned short* lB0 = lB + (w * 2 + 0) * 512;
  unsigned short* lB1 = lB + (w * 2 + 1) * 512;

  f32x4 acc[4][4] = {};
  const int ka = (lane >> 4) * 8;

  for (int k0 = 0; k0 < 128; k0 += 32) {
    __syncthreads();
    async16(a0 + k0, lA0);
    async16(a1 + k0, lA1);
    async16(b0 + k0, lB0);
    async16(b1 + k0, lB1);
    __syncthreads();
    bf16x8 af[4], bfr[4];
#pragma unroll
    for (int mt = 0; mt < 4; mt++)
      af[mt] = *(const bf16x8*)&lA[(wm * 64 + mt * 16 + (lane & 15)) * 32 + ka];
#pragma unroll
    for (int nt = 0; nt < 4; nt++)
      bfr[nt] = *(const bf16x8*)&lB[(wn * 64 + nt * 16 + (lane & 15)) * 32 + ka];
#pragma unroll
    for (int mt = 0; mt < 4; mt++)
#pragma unroll
      for (int nt = 0; nt < 4; nt++)
        acc[mt][nt] = __builtin_amdgcn_mfma_f32_16x16x32_bf16(af[mt], bfr[nt], acc[mt][nt], 0, 0, 0);
  }

  const int col = n0 + wn * 64 + (lane & 15);
  const int rowb = m0 + wm * 64 + (lane >> 4) * 4;
#pragma unroll
  for (int mt = 0; mt < 4; mt++)
#pragma unroll
    for (int nt = 0; nt < 4; nt++)
#pragma unroll
      for (int r = 0; r < 4; r++)
        P[(size_t)(rowb + mt * 16 + r) * 512 + col + nt * 16] = acc[mt][nt][r];
}

// Combine: 256 threads handle ROWS=256/O rows; XCD-pinned.
// Emits: f32 hcat slice (hout), bf16 hcat slice (hbf), the next layer's kNN
// operands DIRECTLY in packed fragment order (pk; KK=O/32), and the bf16
// A-matrix for gemm_proj (a4).
template <int O>
__global__ __launch_bounds__(256) void combine_kernel(
    const float* __restrict__ P, const int* __restrict__ idxo, const float* __restrict__ bias,
    float* __restrict__ hout, unsigned short* __restrict__ hbf, float* __restrict__ xxo,
    unsigned short* __restrict__ pk, unsigned short* __restrict__ a4) {
  constexpr int ROWS = 256 / O;
  const int bb = blockIdx.x & 7;
  const int rt = blockIdx.x >> 3;
  const int r = threadIdx.x / O;
  const int o = threadIdx.x & (O - 1);
  const int row = bb * N_ + rt * ROWS + r;
  __shared__ int idxs[ROWS][K_];
  __shared__ float ps[ROWS][O / 64 > 0 ? O / 64 : 1];
  if (o < K_) idxs[r][o] = idxo[(size_t)row * K_ + o];
  __syncthreads();
  const int base_row = bb * N_;
  float g = -3.4e38f;
#pragma unroll
  for (int k = 0; k < K_; k++) {
    float v = P[(size_t)(base_row + idxs[r][k]) * (2 * O) + o];
    g = fmaxf(g, v);
  }
  float ba = P[(size_t)row * (2 * O) + O + o];
  float val = lrelu(g + ba + bias[o]);
  if (hout) hout[(size_t)row * 512 + o] = val;
  if (hbf) hbf[(size_t)row * 512 + o] = f2bf(val);
  if (pk) {
    unsigned short hb = f2h(val);
    float vh = h2f(hb);
    unsigned short mb = f2h(val - vh);  // Dekker residual, exact in fp32
    const int n = rt * ROWS + r;
    const int tile = n >> 4, rr = n & 15;
    const int kk = o >> 5, cc = o & 31;
    const int lane2 = ((cc >> 3) << 4) + rr, elem = cc & 7;
    const size_t chunk = ((size_t)(bb * 128 + tile) * (O / 32) + kk) * 2 * 512;
    pk[chunk + lane2 * 8 + elem] = hb;
    pk[chunk + 512 + lane2 * 8 + elem] = mb;
  }
  if (a4) a4[(size_t)row * 1024 + o] = f2bf(val);
  if (xxo) {
    float sq = val * val;
#pragma unroll
    for (int off = 32; off > 0; off >>= 1) sq += __shfl_xor(sq, off, 64);
    if constexpr (O == 64) {
      if (o == 0) xxo[row] = sq;
    } else {
      if ((threadIdx.x & 63) == 0) ps[r][o >> 6] = sq;
      __syncthreads();
      if (o == 0) {
        float t = ps[r][0];
#pragma unroll
        for (int u = 1; u < O / 64; u++) t += ps[r][u];
        xxo[row] = t;
      }
    }
  }
}

// Final GEMM: 128x128 tile, BK=32, bf16 MFMA, max-over-rows epilogue; XCD-pinned.
__global__ __launch_bounds__(256) void gemm_final(const unsigned short* __restrict__ A,
                                                  const unsigned short* __restrict__ Bw,
                                                  float* __restrict__ part) {
  const int mt5 = (blockIdx.x & 7) * 16 + (blockIdx.x >> 3);
  const int m0 = mt5 * 128;
  const int n0 = blockIdx.y * 128;
  const int tid = threadIdx.x;
  const int w = tid >> 6, lane = tid & 63;
  const int wm = w & 1, wn = w >> 1;

  __shared__ unsigned short lA[128 * 32];
  __shared__ unsigned short lB[128 * 32];
  __shared__ float ldsred[2][128];

  const int r0 = (w * 2 + 0) * 16 + (lane >> 2);
  const int r1 = (w * 2 + 1) * 16 + (lane >> 2);
  const int ks = (lane & 3) * 8;
  const unsigned short* a0 = A + (size_t)(m0 + r0) * 512 + ks;
  const unsigned short* a1 = A + (size_t)(m0 + r1) * 512 + ks;
  const unsigned short* b0 = Bw + (size_t)(n0 + r0) * 512 + ks;
  const unsigned short* b1 = Bw + (size_t)(n0 + r1) * 512 + ks;
  unsigned short* lA0 = lA + (w * 2 + 0) * 512;
  unsigned short* lA1 = lA + (w * 2 + 1) * 512;
  unsigned short* lB0 = lB + (w * 2 + 0) * 512;
  unsigned short* lB1 = lB + (w * 2 + 1) * 512;

  f32x4 acc[4][4] = {};
  const int ka = (lane >> 4) * 8;

  for (int k0 = 0; k0 < 512; k0 += 32) {
    __syncthreads();
    async16(a0 + k0, lA0);
    async16(a1 + k0, lA1);
    async16(b0 + k0, lB0);
    async16(b1 + k0, lB1);
    __syncthreads();
    bf16x8 af[4], bfr[4];
#pragma unroll
    for (int mt = 0; mt < 4; mt++)
      af[mt] = *(const bf16x8*)&lA[(wm * 64 + mt * 16 + (lane & 15)) * 32 + ka];
#pragma unroll
    for (int nt = 0; nt < 4; nt++)
      bfr[nt] = *(const bf16x8*)&lB[(wn * 64 + nt * 16 + (lane & 15)) * 32 + ka];
#pragma unroll
    for (int mt = 0; mt < 4; mt++)
#pragma unroll
      for (int nt = 0; nt < 4; nt++)
        acc[mt][nt] = __builtin_amdgcn_mfma_f32_16x16x32_bf16(af[mt], bfr[nt], acc[mt][nt], 0, 0, 0);
  }

#pragma unroll
  for (int nt = 0; nt < 4; nt++) {
    float v = -3.4e38f;
#pragma unroll
    for (int mt = 0; mt < 4; mt++)
#pragma unroll
      for (int r = 0; r < 4; r++) v = fmaxf(v, acc[mt][nt][r]);
    v = fmaxf(v, __shfl_xor(v, 16, 64));
    v = fmaxf(v, __shfl_xor(v, 32, 64));
    if (lane < 16) ldsred[wm][wn * 64 + nt * 16 + lane] = v;
  }
  __syncthreads();
  if (tid < 128) {
    float v = fmaxf(ldsred[0][tid], ldsred[1][tid]);
    const int b = blockIdx.x & 7, s5 = blockIdx.x >> 3;
    part[(size_t)(b * 16 + s5) * 1024 + n0 + tid] = v;
  }
}

__global__ void final_reduce(const float* __restrict__ part, const float* __restrict__ bf,
                             float* __restrict__ out) {
  int i = blockIdx.x * 256 + threadIdx.x;
  if (i >= B_ * 1024) return;
  int b = i >> 10, o = i & 1023;
  float m = -3.4e38f;
  for (int s = 0; s < 16; s++) m = fmaxf(m, part[(size_t)(b * 16 + s) * 1024 + o]);
  out[i] = lrelu(m + bf[o]);
}

extern "C" void kernel_launch(void* const* d_in, const int* in_sizes, int n_in, void* d_out,
                              int out_size, void* d_ws, size_t ws_size, hipStream_t stream) {
  (void)in_sizes; (void)n_in; (void)out_size;
  const float* x = (const float*)d_in[0];
  const float* W1 = (const float*)d_in[1];
  const float* b1 = (const float*)d_in[2];
  const float* W2 = (const float*)d_in[3];
  const float* b2 = (const float*)d_in[4];
  const float* W3 = (const float*)d_in[5];
  const float* b3 = (const float*)d_in[6];
  const float* W4 = (const float*)d_in[7];
  const float* b4 = (const float*)d_in[8];
  const float* Wf = (const float*)d_in[9];
  const float* bf = (const float*)d_in[10];

  float* ws = (float*)d_ws;
  float* hcat = ws;                               // B*N*512 floats (32 MB)
  float* P = hcat + (size_t)B_ * N_ * 512;        // B*N*512 floats (32 MB)
  int* idx = (int*)(P + (size_t)B_ * N_ * 512);   // B*N*20 ints
  float* Wp = (float*)(idx + (size_t)B_ * N_ * K_);
  float* part = Wp + 512 * 128;                   // 8*16*1024 floats
  float* xxb = part + 8 * 16 * 1024;              // B*N floats (row norms)
  float* out = (float*)d_out;
  unsigned short* hcat_bf = (unsigned short*)P;   // alias P (dead after layer-4)
  unsigned short* Wf_bf = hcat_bf + (size_t)B_ * N_ * 512;
  unsigned short* A4_bf = (unsigned short*)hcat + 512;  // interleaved, stride 1024 ushorts
  unsigned short* Wp_bf = (unsigned short*)part;        // part dead until gemm_final

  // Optional fused-bf16 hcat buffer (16 MB) past xxb; used only if ws fits.
  float* ws_end = xxb + (size_t)B_ * N_;
  unsigned short* hcatbf2 = (unsigned short*)ws_end;
  const size_t need = ((char*)(hcatbf2 + (size_t)B_ * N_ * 512)) - (char*)d_ws;
  const bool fused = ws_size >= need;

  // Packed kNN operand buffers (producers write fragment order directly):
  //   Pk23 at P+8MB (C=32 layer-1: 2MB; C=64 layers 2-3: 4MB);
  //   Pk4  at P+16MB (C=128: 8MB).
  unsigned short* Pk23 = (unsigned short*)(P + (size_t)2097152);  // +8 MB
  unsigned short* Pk4 = (unsigned short*)(P + (size_t)4194304);   // +16 MB

  dim3 knng16(N_ / 16 * B_);   // Q=16: 1024 blocks x 1024 thr
  dim3 knng32q(N_ / 32 * B_);  // Q=32: 512 blocks x 512 thr

  // Layer 1: C=3 (padded to 32) -> O=64; q16 kNN (selection-bound layer).
  prep_wp<<<(2 * 64 * 3 + 255) / 256, 256, 0, stream>>>(W1, Wp, nullptr, 64, 3);
  split32_x<<<(B_ * N_ * 32 + 255) / 256, 256, 0, stream>>>(x, Pk23, xxb);
  knn_mfma_q16<32><<<knng16, 1024, 0, stream>>>(Pk23, xxb, idx);
  proj_kernel<3, 128><<<dim3(B_ * N_ / 16, 1), 128, 0, stream>>>(x, 3, Wp, P);
  combine_kernel<64><<<B_ * N_ / 4, 256, 0, stream>>>(
      P, idx, b1, hcat + 0, fused ? hcatbf2 + 0 : nullptr, xxb, Pk23, nullptr);

  // Layer 2: C=64 -> O=64; q32 kNN.
  prep_wp<<<(2 * 64 * 64 + 255) / 256, 256, 0, stream>>>(W2, Wp, nullptr, 64, 64);
  knn_mfma_q32<64><<<knng32q, 512, 0, stream>>>(Pk23, xxb, idx);
  proj_kernel<64, 128><<<dim3(B_ * N_ / 16, 1), 128, 0, stream>>>(hcat + 0, 512, Wp, P);
  combine_kernel<64><<<B_ * N_ / 4, 256, 0, stream>>>(
      P, idx, b2, hcat + 64, fused ? hcatbf2 + 64 : nullptr, xxb, Pk23, nullptr);

  // Layer 3: C=64 -> O=128; q32 kNN.
  prep_wp<<<(2 * 128 * 64 + 255) / 256, 256, 0, stream>>>(W3, Wp, nullptr, 128, 64);
  knn_mfma_q32<64><<<knng32q, 512, 0, stream>>>(Pk23, xxb, idx);
  proj_kernel<64, 256><<<dim3(B_ * N_ / 16, 1), 256, 0, stream>>>(hcat + 64, 512, Wp, P);
  combine_kernel<128><<<B_ * N_ / 2, 256, 0, stream>>>(
      P, idx, b3, fused ? nullptr : hcat + 128, fused ? hcatbf2 + 128 : nullptr, xxb, Pk4,
      A4_bf);

  // Layer 4: C=128 -> O=256; q32 kNN; proj via bf16 MFMA (prep_wp emits bf16).
  prep_wp<<<(2 * 256 * 128 + 255) / 256, 256, 0, stream>>>(W4, Wp, Wp_bf, 256, 128);
  knn_mfma_q32<128><<<knng32q, 512, 0, stream>>>(Pk4, xxb, idx);
  gemm_proj<<<dim3(B_ * N_ / 128, 4), 256, 0, stream>>>(A4_bf, 1024, Wp_bf, P);
  combine_kernel<256><<<B_ * N_, 256, 0, stream>>>(
      P, idx, b4, fused ? nullptr : hcat + 256, fused ? hcatbf2 + 256 : nullptr, nullptr,
      nullptr, nullptr);

  // Final 1x1 conv via bf16 MFMA + fused max-over-rows.
  if (!fused)
    cvt_bf16<<<(B_ * N_ * 512 / 4 + 255) / 256, 256, 0, stream>>>(
        (const float4*)hcat, (ushort4*)hcat_bf, B_ * N_ * 512 / 4);
  cvt_bf16<<<(1024 * 512 / 4 + 255) / 256, 256, 0, stream>>>(
      (const float4*)Wf, (ushort4*)Wf_bf, 1024 * 512 / 4);
  gemm_final<<<dim3(128, 8), 256, 0, stream>>>(fused ? hcatbf2 : hcat_bf, Wf_bf, part);
  final_reduce<<<(B_ * 1024 + 255) / 256, 256, 0, stream>>>(part, bf, out);
}